// Round 4
// baseline (934.172 us; speedup 1.0000x reference)
//
#include <hip/hip_runtime.h>
#include <hip/hip_bf16.h>

// B=4, S=2048, D=768, H=12, DH=64
// out = [ ctx (B*S*D fp32) | probs (B*H*S*S fp32) ]
#define BB 4
#define SS 2048
#define DD 768
#define HH 12

typedef unsigned short u16t;
typedef unsigned char  u8t;
typedef unsigned int   u32t;
typedef __attribute__((ext_vector_type(8)))  short bf16x8;
typedef __attribute__((ext_vector_type(4)))  float f32x4;
typedef __attribute__((ext_vector_type(16))) float f32x16;

union FragU { bf16x8 v; ushort4 h[2]; uint4 u; u32t g[4]; };

__device__ __forceinline__ u16t f2bf(float f) {
  union { float fv; u32t u; } x; x.fv = f;
  u32t r = x.u + 0x7FFFu + ((x.u >> 16) & 1u);   // RNE f32 -> bf16
  return (u16t)(r >> 16);
}

__device__ __forceinline__ u32t pkbf2(float a, float b) {  // 2xf32 -> packed bf16x2
  __hip_bfloat162 h2 = __float22bfloat162_rn(make_float2(a, b));
  union { __hip_bfloat162 h; u32t u; } c; c.h = h2;
  return c.u;
}

// pack 4 bool bytes (0/1) of a u32 into bits 0..3
__device__ __forceinline__ u32t pack4(u32t w) {
  return ((w & 0x01010101u) * 0x01020408u) >> 24;
}
__device__ __forceinline__ u32t pack16b(uint4 v) {
  return pack4(v.x) | (pack4(v.y) << 4) | (pack4(v.z) << 8) | (pack4(v.w) << 12);
}
__device__ __forceinline__ u32t pack_i4(int4 v) {
  return (v.x ? 1u : 0u) | ((v.y ? 1u : 0u) << 1) | ((v.z ? 1u : 0u) << 2) | ((v.w ? 1u : 0u) << 3);
}
__device__ __forceinline__ u32t pack_f4(float4 v) {
  return (v.x != 0.f ? 1u : 0u) | ((v.y != 0.f ? 1u : 0u) << 1) |
         ((v.z != 0.f ? 1u : 0u) << 2) | ((v.w != 0.f ? 1u : 0u) << 3);
}

// per-lane mask tile: 128 bits (4 words of 32 k) for one q-row at col kt*128
__device__ __forceinline__ uint4 load_mask_tile(const void* __restrict__ maskp,
                                                int fmt, size_t ebase)
{
  uint4 r;
  if (fmt == 1) {
    const uint4* s = (const uint4*)((const u8t*)maskp + ebase);
    uint4 a0 = s[0], a1 = s[1], a2 = s[2], a3 = s[3];
    uint4 a4 = s[4], a5 = s[5], a6 = s[6], a7 = s[7];
    r.x = pack16b(a0) | (pack16b(a1) << 16);
    r.y = pack16b(a2) | (pack16b(a3) << 16);
    r.z = pack16b(a4) | (pack16b(a5) << 16);
    r.w = pack16b(a6) | (pack16b(a7) << 16);
  } else if (fmt == 0) {
    const int4* s = (const int4*)((const int*)maskp + ebase);
    u32t wds[4];
#pragma unroll
    for (int c = 0; c < 4; ++c) {
      u32t a = 0;
#pragma unroll
      for (int j = 0; j < 8; ++j) a |= pack_i4(s[c * 8 + j]) << (j * 4);
      wds[c] = a;
    }
    r.x = wds[0]; r.y = wds[1]; r.z = wds[2]; r.w = wds[3];
  } else {
    const float4* s = (const float4*)((const float*)maskp + ebase);
    u32t wds[4];
#pragma unroll
    for (int c = 0; c < 4; ++c) {
      u32t a = 0;
#pragma unroll
      for (int j = 0; j < 8; ++j) a |= pack_f4(s[c * 8 + j]) << (j * 4);
      wds[c] = a;
    }
    r.x = wds[0]; r.y = wds[1]; r.z = wds[2]; r.w = wds[3];
  }
  return r;
}

// ---- mask dtype detector: flag = 0 int32(0/1), 1 bool bytes, 2 float32(0/1) ----
__global__ void detect_kernel(const u32t* __restrict__ mp, int* __restrict__ flag)
{
  __shared__ int s_isb, s_isf;
  if (threadIdx.x == 0) { s_isb = 0; s_isf = 0; }
  __syncthreads();
  int isb = 0, isf = 0;
  for (int i = threadIdx.x; i < 16384; i += 256) {
    u32t v = mp[i];
    if ((v & 0xFF000000u) == 0x3F000000u) isf = 1;
    else if (v & 0xFFFFFF00u) isb = 1;
  }
  if (isb) atomicOr(&s_isb, 1);
  if (isf) atomicOr(&s_isf, 1);
  __syncthreads();
  if (threadIdx.x == 0) *flag = s_isf ? 2 : (s_isb ? 1 : 0);
}

// ---- shared GEMM tile: acc[8] = X[m0..+64][:] @ W[:][n0..+128] (bf16 MFMA) ----
__device__ __forceinline__ void proj_tile_gemm(const float* __restrict__ X,
    const float* __restrict__ W, int m0, int n0, int t,
    u16t* __restrict__ Al, u16t* __restrict__ Bl, f32x4 acc[8])
{
  const int w = t >> 6, l = t & 63;
  const int lq = l & 15, lg = l >> 4;
  const int ar = t >> 2, ac = (t & 3) * 8;
  const int bn = (t & 15) * 8;

  for (int kk = 0; kk < DD; kk += 32) {
    {
      const float* s = X + (size_t)(m0 + ar) * DD + kk + ac;
      float4 f0 = *(const float4*)s;
      float4 f1 = *(const float4*)(s + 4);
      u16t* d = &Al[ar * 40 + ac];
      d[0] = f2bf(f0.x); d[1] = f2bf(f0.y); d[2] = f2bf(f0.z); d[3] = f2bf(f0.w);
      d[4] = f2bf(f1.x); d[5] = f2bf(f1.y); d[6] = f2bf(f1.z); d[7] = f2bf(f1.w);
    }
#pragma unroll
    for (int rep = 0; rep < 2; ++rep) {
      const int c = (t >> 4) + rep * 16;
      const float* s = W + (size_t)(kk + c) * DD + n0 + bn;
      float4 f0 = *(const float4*)s;
      float4 f1 = *(const float4*)(s + 4);
      float fv[8] = {f0.x, f0.y, f0.z, f0.w, f1.x, f1.y, f1.z, f1.w};
#pragma unroll
      for (int e = 0; e < 8; ++e) {
        const int n = bn + e;
        Bl[n * 40 + (c ^ (((n >> 3) & 3) * 8))] = f2bf(fv[e]);
      }
    }
    __syncthreads();
    FragU a;
    const int arow = w * 16 + lq;
    a.h[0] = *(const ushort4*)&Al[arow * 40 + 4 * lg];
    a.h[1] = *(const ushort4*)&Al[arow * 40 + 4 * lg + 16];
#pragma unroll
    for (int nt = 0; nt < 8; ++nt) {
      const int bcol = nt * 16 + lq;
      const int xb = ((bcol >> 3) & 3) * 8;
      FragU bfr;
      bfr.h[0] = *(const ushort4*)&Bl[bcol * 40 + ((4 * lg) ^ xb)];
      bfr.h[1] = *(const ushort4*)&Bl[bcol * 40 + ((4 * lg + 16) ^ xb)];
      acc[nt] = __builtin_amdgcn_mfma_f32_16x16x32_bf16(a.v, bfr.v, acc[nt], 0, 0, 0);
    }
    __syncthreads();
  }
}

// ---- proj Q/K: out layout [b][h][s][64] bf16 ----
__global__ __launch_bounds__(256)
void proj_qk_kernel(const float* __restrict__ X, const float* __restrict__ W,
                    const float* __restrict__ bias, u16t* __restrict__ out)
{
  __shared__ u16t Al[64 * 40];
  __shared__ u16t Bl[128 * 40];
  const int t = threadIdx.x;
  const int w = t >> 6, l = t & 63;
  const int lq = l & 15, lg = l >> 4;
  const int m0 = blockIdx.x * 64;
  const int n0 = blockIdx.y * 128;
  const int b = m0 >> 11;

  f32x4 acc[8];
#pragma unroll
  for (int i = 0; i < 8; ++i)
#pragma unroll
    for (int r = 0; r < 4; ++r) acc[i][r] = 0.f;

  proj_tile_gemm(X, W, m0, n0, t, Al, Bl, acc);

#pragma unroll
  for (int nt = 0; nt < 8; ++nt) {
    const int n = n0 + nt * 16 + lq;
    const int h = n >> 6, dh = n & 63;
    const float bb = bias[n];
#pragma unroll
    for (int r = 0; r < 4; ++r) {
      const int s = (m0 & 2047) + w * 16 + 4 * lg + r;
      out[((size_t)(b * HH + h) * SS + s) * 64 + dh] = f2bf(acc[nt][r] + bb);
    }
  }
}

// ---- proj V: out layout [b][h][dh][s] bf16 (transposed via LDS) ----
__global__ __launch_bounds__(256)
void proj_v_kernel(const float* __restrict__ X, const float* __restrict__ W,
                   const float* __restrict__ bias, u16t* __restrict__ out)
{
  __shared__ u16t Al[64 * 40];
  __shared__ u16t Bl[128 * 40];
  __shared__ u16t Tl[128 * 72];
  const int t = threadIdx.x;
  const int w = t >> 6, l = t & 63;
  const int lq = l & 15, lg = l >> 4;
  const int m0 = blockIdx.x * 64;
  const int n0 = blockIdx.y * 128;
  const int b = m0 >> 11;

  f32x4 acc[8];
#pragma unroll
  for (int i = 0; i < 8; ++i)
#pragma unroll
    for (int r = 0; r < 4; ++r) acc[i][r] = 0.f;

  proj_tile_gemm(X, W, m0, n0, t, Al, Bl, acc);

#pragma unroll
  for (int nt = 0; nt < 8; ++nt) {
    const float bb = bias[n0 + nt * 16 + lq];
#pragma unroll
    for (int r = 0; r < 4; ++r)
      Tl[(nt * 16 + lq) * 72 + w * 16 + 4 * lg + r] = f2bf(acc[nt][r] + bb);
  }
  __syncthreads();

  const int rowl = t >> 1;
  const int half = t & 1;
  const int ncol = n0 + rowl;
  const int h = ncol >> 6, dh = ncol & 63;
  const int s = (m0 & 2047) + half * 32;
  u16t* dst = out + ((size_t)(b * HH + h) * 64 + dh) * SS + s;
#pragma unroll
  for (int i = 0; i < 4; ++i) {
    uint4 vv = *(const uint4*)&Tl[rowl * 72 + half * 32 + i * 8];
    *(uint4*)(dst + i * 8) = vv;
  }
}

// ---- fused attention: 1 wave / 32 q-rows, NO LDS, NO barriers, direct-from-L2 ----
// Swapped QK^T (A=K, B=Q): acc[r] = S[k = c*32 + (r&3)+8*(r>>2)+4*hh][q = qbase+lq]
__global__ __launch_bounds__(64, 3)
void attn_kernel(const u16t* __restrict__ Qh, const u16t* __restrict__ Kh,
                 const u16t* __restrict__ Vh, const void* __restrict__ maskp,
                 const int* __restrict__ flagp,
                 float* __restrict__ ctx, float* __restrict__ probs)
{
  const int l = threadIdx.x;
  const int lq = l & 31;     // q-col / row within 32
  const int hh = l >> 5;     // lane half

  const int bid = (int)blockIdx.x;               // 0..3071
  const int lid = (bid & 7) * 384 + (bid >> 3);  // bijective XCD chunking (3072 = 8*384)
  const int bh = lid >> 6;                       // 0..47 (6 heads per XCD chunk)
  const int qt = lid & 63;                       // 0..63
  const int b = bh / HH;
  const int fmt = *flagp;
  const int qbase = qt * 32;

  const u16t* qh = Qh + (size_t)bh * SS * 64;
  const u16t* kh = Kh + (size_t)bh * SS * 64;
  const u16t* vh = Vh + (size_t)bh * SS * 64;

  // Q fragments (B operand): bq[dhc] holds Q[qbase+lq][dhc*16 + 8*hh + j]
  FragU bq[4];
  {
    const u16t* qp = qh + (size_t)(qbase + lq) * 64 + 8 * hh;
#pragma unroll
    for (int dhc = 0; dhc < 4; ++dhc) bq[dhc].u = *(const uint4*)(qp + dhc * 16);
  }

  const size_t mrowbase = (size_t)b * SS * SS + (size_t)(qbase + lq) * SS;

  // QK^T chunk: 4 MFMA over dh=64; A = K rows (c*32+lq) direct from global (L2)
#define QKT_CHUNK(kt_, c_, accv)                                                  \
  {                                                                               \
    const u16t* kp = kh + (size_t)((kt_) * 128 + (c_) * 32 + lq) * 64 + 8 * hh;   \
    _Pragma("unroll")                                                             \
    for (int i = 0; i < 16; ++i) (accv)[i] = 0.f;                                 \
    __builtin_amdgcn_s_setprio(1);                                                \
    _Pragma("unroll")                                                             \
    for (int dhc = 0; dhc < 4; ++dhc) {                                           \
      FragU ak;                                                                   \
      ak.u = *(const uint4*)(kp + dhc * 16);                                      \
      (accv) = __builtin_amdgcn_mfma_f32_32x32x16_bf16(ak.v, bq[dhc].v, (accv), 0, 0, 0); \
    }                                                                             \
    __builtin_amdgcn_s_setprio(0);                                                \
  }

  float m = -3.0e38f, sm = 0.f;

  // ---------------- sweep 1: online row max & exp-sum ----------------
  for (int kt = 0; kt < 16; ++kt) {
    uint4 mw = load_mask_tile(maskp, fmt, mrowbase + kt * 128);
    u32t mwv[4] = {mw.x, mw.y, mw.z, mw.w};
#pragma unroll
    for (int c = 0; c < 4; ++c) {
      f32x16 acc;
      QKT_CHUNK(kt, c, acc)
      float scv[16];
      float tm = -3.0e38f;
#pragma unroll
      for (int r = 0; r < 16; ++r) {
        float s = acc[r] * 0.125f;
        if ((mwv[c] >> ((r & 3) + 8 * (r >> 2) + 4 * hh)) & 1) s = -1.0e9f;
        scv[r] = s;
        tm = fmaxf(tm, s);
      }
      tm = fmaxf(tm, __shfl_xor(tm, 32));
      const float nm = fmaxf(m, tm);
      float ss = 0.f;
#pragma unroll
      for (int r = 0; r < 16; ++r) ss += __expf(scv[r] - nm);
      ss += __shfl_xor(ss, 32);
      sm = sm * __expf(m - nm) + ss;
      m = nm;
    }
  }

  const float inv = 1.0f / sm;
  f32x16 acco[2];
#pragma unroll
  for (int i = 0; i < 16; ++i) { acco[0][i] = 0.f; acco[1][i] = 0.f; }

  // ---------------- sweep 2: recompute -> probs (full-line stores) + PV ----------------
  for (int kt = 0; kt < 16; ++kt) {
    uint4 mw = load_mask_tile(maskp, fmt, mrowbase + kt * 128);
    u32t mwv[4] = {mw.x, mw.y, mw.z, mw.w};
    const size_t prow = ((size_t)bh * SS + qbase + lq) * SS + kt * 128;

#pragma unroll
    for (int c = 0; c < 4; ++c) {
      f32x16 acc;
      QKT_CHUNK(kt, c, acc)
      float p[16];
#pragma unroll
      for (int r = 0; r < 16; ++r) {
        float s = acc[r] * 0.125f;
        if ((mwv[c] >> ((r & 3) + 8 * (r >> 2) + 4 * hh)) & 1) s = -1.0e9f;
        p[r] = __expf(s - m) * inv;
      }
      // full hh-pair exchange: o[j] = partner's p[j]  (k of p[r] = c*32+8*(r>>2)+(r&3)+4*hh)
      float o[16];
#pragma unroll
      for (int j = 0; j < 16; ++j) o[j] = __shfl_xor(p[j], 32);

      // probs: hh=0 lane writes k 0..15 (64 B), hh=1 writes k 16..31 -> full 128B line/row
      {
        float* pp = probs + prow + c * 32 + hh * 16;
        float4 f0, f1, f2, f3;
        f0.x = hh ? o[8]  : p[0];  f0.y = hh ? o[9]  : p[1];
        f0.z = hh ? o[10] : p[2];  f0.w = hh ? o[11] : p[3];
        f1.x = hh ? p[8]  : o[0];  f1.y = hh ? p[9]  : o[1];
        f1.z = hh ? p[10] : o[2];  f1.w = hh ? p[11] : o[3];
        f2.x = hh ? o[12] : p[4];  f2.y = hh ? o[13] : p[5];
        f2.z = hh ? o[14] : p[6];  f2.w = hh ? o[15] : p[7];
        f3.x = hh ? p[12] : o[4];  f3.y = hh ? p[13] : o[5];
        f3.z = hh ? p[14] : o[6];  f3.w = hh ? p[15] : o[7];
        *(float4*)(pp + 0)  = f0;
        *(float4*)(pp + 4)  = f1;
        *(float4*)(pp + 8)  = f2;
        *(float4*)(pp + 12) = f3;
      }

      // PV B-fragments: pf[k16] value j (k = k16*16 + 8*hh + j):
      //   j<4: hh ? o[8*k16+4+j] : p[8*k16+j];  j>=4: hh ? p[8*k16+4+(j-4)] : o[8*k16+(j-4)]
      FragU pf[2];
#pragma unroll
      for (int k16 = 0; k16 < 2; ++k16) {
        const int base = 8 * k16;
        pf[k16].g[0] = pkbf2(hh ? o[base + 4] : p[base + 0], hh ? o[base + 5] : p[base + 1]);
        pf[k16].g[1] = pkbf2(hh ? o[base + 6] : p[base + 2], hh ? o[base + 7] : p[base + 3]);
        pf[k16].g[2] = pkbf2(hh ? p[base + 4] : o[base + 0], hh ? p[base + 5] : o[base + 1]);
        pf[k16].g[3] = pkbf2(hh ? p[base + 6] : o[base + 2], hh ? p[base + 7] : o[base + 3]);
      }

      // PV: O^T[d][q] += V^T-chunk x P-chunk ; V direct from global (L2)
      __builtin_amdgcn_s_setprio(1);
#pragma unroll
      for (int dhalf = 0; dhalf < 2; ++dhalf) {
        const u16t* vp = vh + (size_t)(dhalf * 32 + lq) * SS + kt * 128 + c * 32 + 8 * hh;
#pragma unroll
        for (int k16 = 0; k16 < 2; ++k16) {
          FragU av;
          av.u = *(const uint4*)(vp + k16 * 16);
          acco[dhalf] = __builtin_amdgcn_mfma_f32_32x32x16_bf16(av.v, pf[k16].v, acco[dhalf], 0, 0, 0);
        }
      }
      __builtin_amdgcn_s_setprio(0);
    }
  }

  // ctx epilogue: O[q = qbase+lq][d = h*64 + dhalf*32 + (r&3)+8*(r>>2)+4*hh]
  {
    const int h = bh % HH;
    const size_t cbase = ((size_t)b * SS + qbase + lq) * DD + h * 64;
#pragma unroll
    for (int dhalf = 0; dhalf < 2; ++dhalf) {
#pragma unroll
      for (int g = 0; g < 4; ++g) {
        float4 f4;
        f4.x = acco[dhalf][4 * g + 0]; f4.y = acco[dhalf][4 * g + 1];
        f4.z = acco[dhalf][4 * g + 2]; f4.w = acco[dhalf][4 * g + 3];
        *(float4*)(ctx + cbase + dhalf * 32 + 8 * g + 4 * hh) = f4;
      }
    }
  }
#undef QKT_CHUNK
}

extern "C" void kernel_launch(void* const* d_in, const int* in_sizes, int n_in,
                              void* d_out, int out_size, void* d_ws, size_t ws_size,
                              hipStream_t stream)
{
  const float* q   = (const float*)d_in[0];
  const float* k   = (const float*)d_in[1];
  const float* v   = (const float*)d_in[2];
  const void*  msk = d_in[3];
  const float* Wq  = (const float*)d_in[4];
  const float* bq  = (const float*)d_in[5];
  const float* Wk  = (const float*)d_in[6];
  const float* bk  = (const float*)d_in[7];
  const float* Wv  = (const float*)d_in[8];
  const float* bv  = (const float*)d_in[9];
  (void)in_sizes; (void)n_in; (void)out_size; (void)ws_size;

  const size_t NE = (size_t)BB * SS * DD;
  u16t* Qb = (u16t*)d_ws;
  u16t* Kb = Qb + NE;
  u16t* Vb = Kb + NE;
  int* flag = (int*)(Vb + NE);

  float* ctx   = (float*)d_out;
  float* probs = ctx + NE;

  detect_kernel<<<1, 256, 0, stream>>>((const u32t*)msk, flag);

  dim3 pg(BB * SS / 64, DD / 128);
  proj_qk_kernel<<<pg, 256, 0, stream>>>(q, Wq, bq, Qb);
  proj_qk_kernel<<<pg, 256, 0, stream>>>(k, Wk, bk, Kb);
  proj_v_kernel <<<pg, 256, 0, stream>>>(v, Wv, bv, Vb);

  attn_kernel<<<dim3(3072), 64, 0, stream>>>(Qb, Kb, Vb, msk, flag, ctx, probs);
}

// Round 6
// 429.377 us; speedup vs baseline: 2.1756x; 2.1756x over previous
//
#include <hip/hip_runtime.h>
#include <hip/hip_bf16.h>

// B=4, S=2048, D=768, H=12, DH=64
// out = [ ctx (B*S*D fp32) | probs (B*H*S*S fp32) ]
#define BB 4
#define SS 2048
#define DD 768
#define HH 12

typedef unsigned short u16t;
typedef unsigned char  u8t;
typedef unsigned int   u32t;
typedef __attribute__((ext_vector_type(8)))  short bf16x8;
typedef __attribute__((ext_vector_type(4)))  float f32x4;

union FragU { bf16x8 v; ushort4 h[2]; uint4 u; u32t g[4]; };

__device__ __forceinline__ u16t f2bf(float f) {
  union { float fv; u32t u; } x; x.fv = f;
  u32t r = x.u + 0x7FFFu + ((x.u >> 16) & 1u);   // RNE f32 -> bf16
  return (u16t)(r >> 16);
}

__device__ __forceinline__ u32t pkbf2(float a, float b) {  // 2xf32 -> packed bf16x2
  __hip_bfloat162 h2 = __float22bfloat162_rn(make_float2(a, b));
  union { __hip_bfloat162 h; u32t u; } c; c.h = h2;
  return c.u;
}

__device__ __forceinline__ u32t pack4(u32t w) {
  return ((w & 0x01010101u) * 0x01020408u) >> 24;
}
__device__ __forceinline__ u32t pack16b(uint4 v) {
  return pack4(v.x) | (pack4(v.y) << 4) | (pack4(v.z) << 8) | (pack4(v.w) << 12);
}
__device__ __forceinline__ u32t pack_i4(int4 v) {
  return (v.x ? 1u : 0u) | ((v.y ? 1u : 0u) << 1) | ((v.z ? 1u : 0u) << 2) | ((v.w ? 1u : 0u) << 3);
}
__device__ __forceinline__ u32t pack_f4(float4 v) {
  return (v.x != 0.f ? 1u : 0u) | ((v.y != 0.f ? 1u : 0u) << 1) |
         ((v.z != 0.f ? 1u : 0u) << 2) | ((v.w != 0.f ? 1u : 0u) << 3);
}

// ---- mask dtype detector: flag = 0 int32(0/1), 1 bool bytes, 2 float32(0/1) ----
__global__ void detect_kernel(const u32t* __restrict__ mp, int* __restrict__ flag)
{
  __shared__ int s_isb, s_isf;
  if (threadIdx.x == 0) { s_isb = 0; s_isf = 0; }
  __syncthreads();
  int isb = 0, isf = 0;
  for (int i = threadIdx.x; i < 16384; i += 256) {
    u32t v = mp[i];
    if ((v & 0xFF000000u) == 0x3F000000u) isf = 1;
    else if (v & 0xFFFFFF00u) isb = 1;
  }
  if (isb) atomicOr(&s_isb, 1);
  if (isf) atomicOr(&s_isf, 1);
  __syncthreads();
  if (threadIdx.x == 0) *flag = s_isf ? 2 : (s_isb ? 1 : 0);
}

// ---- mask pre-pack: pm[row = b*S+q][c] bit j = mask[b][q][c*32+j]  (2 MB) ----
__global__ __launch_bounds__(256)
void mask_pack_kernel(const void* __restrict__ msk, const int* __restrict__ flagp,
                      u32t* __restrict__ pm)
{
  const int gid = blockIdx.x * 256 + threadIdx.x;   // 0 .. 524287
  const int row = gid >> 6, c = gid & 63;
  const int fmt = *flagp;
  const size_t src = (size_t)(row >> 11) * SS * SS + (size_t)(row & 2047) * SS + c * 32;
  u32t bits;
  if (fmt == 1) {
    const uint4* s = (const uint4*)((const u8t*)msk + src);
    bits = pack16b(s[0]) | (pack16b(s[1]) << 16);
  } else if (fmt == 0) {
    const int4* s = (const int4*)((const int*)msk + src);
    bits = 0;
#pragma unroll
    for (int j = 0; j < 8; ++j) bits |= pack_i4(s[j]) << (j * 4);
  } else {
    const float4* s = (const float4*)((const float*)msk + src);
    bits = 0;
#pragma unroll
    for (int j = 0; j < 8; ++j) bits |= pack_f4(s[j]) << (j * 4);
  }
  pm[(size_t)row * 64 + c] = bits;
}

// ---- shared GEMM tile: acc[8] = X[m0..+64][:] @ W[:][n0..+128] (bf16 MFMA) ----
__device__ __forceinline__ void proj_tile_gemm(const float* __restrict__ X,
    const float* __restrict__ W, int m0, int n0, int t,
    u16t* __restrict__ Al, u16t* __restrict__ Bl, f32x4 acc[8])
{
  const int w = t >> 6, l = t & 63;
  const int lq = l & 15, lg = l >> 4;
  const int ar = t >> 2, ac = (t & 3) * 8;
  const int bn = (t & 15) * 8;

  for (int kk = 0; kk < DD; kk += 32) {
    {
      const float* s = X + (size_t)(m0 + ar) * DD + kk + ac;
      float4 f0 = *(const float4*)s;
      float4 f1 = *(const float4*)(s + 4);
      u16t* d = &Al[ar * 40 + ac];
      d[0] = f2bf(f0.x); d[1] = f2bf(f0.y); d[2] = f2bf(f0.z); d[3] = f2bf(f0.w);
      d[4] = f2bf(f1.x); d[5] = f2bf(f1.y); d[6] = f2bf(f1.z); d[7] = f2bf(f1.w);
    }
#pragma unroll
    for (int rep = 0; rep < 2; ++rep) {
      const int c = (t >> 4) + rep * 16;
      const float* s = W + (size_t)(kk + c) * DD + n0 + bn;
      float4 f0 = *(const float4*)s;
      float4 f1 = *(const float4*)(s + 4);
      float fv[8] = {f0.x, f0.y, f0.z, f0.w, f1.x, f1.y, f1.z, f1.w};
#pragma unroll
      for (int e = 0; e < 8; ++e) {
        const int n = bn + e;
        Bl[n * 40 + (c ^ (((n >> 3) & 3) * 8))] = f2bf(fv[e]);
      }
    }
    __syncthreads();
    FragU a;
    const int arow = w * 16 + lq;
    a.h[0] = *(const ushort4*)&Al[arow * 40 + 4 * lg];
    a.h[1] = *(const ushort4*)&Al[arow * 40 + 4 * lg + 16];
#pragma unroll
    for (int nt = 0; nt < 8; ++nt) {
      const int bcol = nt * 16 + lq;
      const int xb = ((bcol >> 3) & 3) * 8;
      FragU bfr;
      bfr.h[0] = *(const ushort4*)&Bl[bcol * 40 + ((4 * lg) ^ xb)];
      bfr.h[1] = *(const ushort4*)&Bl[bcol * 40 + ((4 * lg + 16) ^ xb)];
      acc[nt] = __builtin_amdgcn_mfma_f32_16x16x32_bf16(a.v, bfr.v, acc[nt], 0, 0, 0);
    }
    __syncthreads();
  }
}

// ---- proj Q/K: out layout [b][h][s][64] bf16 ----
__global__ __launch_bounds__(256)
void proj_qk_kernel(const float* __restrict__ X, const float* __restrict__ W,
                    const float* __restrict__ bias, u16t* __restrict__ out)
{
  __shared__ u16t Al[64 * 40];
  __shared__ u16t Bl[128 * 40];
  const int t = threadIdx.x;
  const int w = t >> 6, l = t & 63;
  const int lq = l & 15, lg = l >> 4;
  const int m0 = blockIdx.x * 64;
  const int n0 = blockIdx.y * 128;
  const int b = m0 >> 11;

  f32x4 acc[8];
#pragma unroll
  for (int i = 0; i < 8; ++i)
#pragma unroll
    for (int r = 0; r < 4; ++r) acc[i][r] = 0.f;

  proj_tile_gemm(X, W, m0, n0, t, Al, Bl, acc);

#pragma unroll
  for (int nt = 0; nt < 8; ++nt) {
    const int n = n0 + nt * 16 + lq;
    const int h = n >> 6, dh = n & 63;
    const float bb = bias[n];
#pragma unroll
    for (int r = 0; r < 4; ++r) {
      const int s = (m0 & 2047) + w * 16 + 4 * lg + r;
      out[((size_t)(b * HH + h) * SS + s) * 64 + dh] = f2bf(acc[nt][r] + bb);
    }
  }
}

// ---- proj V: out layout [b][h][dh][s] bf16 (transposed via LDS) ----
__global__ __launch_bounds__(256)
void proj_v_kernel(const float* __restrict__ X, const float* __restrict__ W,
                   const float* __restrict__ bias, u16t* __restrict__ out)
{
  __shared__ u16t Al[64 * 40];
  __shared__ u16t Bl[128 * 40];
  __shared__ u16t Tl[128 * 72];
  const int t = threadIdx.x;
  const int w = t >> 6, l = t & 63;
  const int lq = l & 15, lg = l >> 4;
  const int m0 = blockIdx.x * 64;
  const int n0 = blockIdx.y * 128;
  const int b = m0 >> 11;

  f32x4 acc[8];
#pragma unroll
  for (int i = 0; i < 8; ++i)
#pragma unroll
    for (int r = 0; r < 4; ++r) acc[i][r] = 0.f;

  proj_tile_gemm(X, W, m0, n0, t, Al, Bl, acc);

#pragma unroll
  for (int nt = 0; nt < 8; ++nt) {
    const float bb = bias[n0 + nt * 16 + lq];
#pragma unroll
    for (int r = 0; r < 4; ++r)
      Tl[(nt * 16 + lq) * 72 + w * 16 + 4 * lg + r] = f2bf(acc[nt][r] + bb);
  }
  __syncthreads();

  const int rowl = t >> 1;
  const int half = t & 1;
  const int ncol = n0 + rowl;
  const int h = ncol >> 6, dh = ncol & 63;
  const int s = (m0 & 2047) + half * 32;
  u16t* dst = out + ((size_t)(b * HH + h) * 64 + dh) * SS + s;
#pragma unroll
  for (int i = 0; i < 4; ++i) {
    uint4 vv = *(const uint4*)&Tl[rowl * 72 + half * 32 + i * 8];
    *(uint4*)(dst + i * 8) = vv;
  }
}

// ---- fused attention: 16x16 MFMA, 4 waves x 16 q-rows, 64-row K/V tiles,
//      double-buffered DMA staging, 2-phase pipeline, fixed-max softmax ----
// Swapped QK^T (A=K, B=Q): lane(lq,lg) holds S[k=nt*16+4lg+r][q=qbase+lq].
// P (same k-map) feeds PV as the A-operand directly; zero shuffles, zero P-LDS.
__global__ __launch_bounds__(256, 4)
void attn_kernel(const u16t* __restrict__ Qh, const u16t* __restrict__ Kh,
                 const u16t* __restrict__ Vh, const u32t* __restrict__ pm,
                 float* __restrict__ ctx, float* __restrict__ probs)
{
  __shared__ u16t Kl[2][64 * 64];   // [kr][d ^ ((kr&7)*8)], dbuf, 16 KB
  __shared__ u16t Vt[2][64 * 64];   // [dh][k ^ ((dh&7)*8)], dbuf, 16 KB

  const int t = threadIdx.x;
  const int w = t >> 6, l = t & 63;
  const int lq = l & 15, lg = l >> 4;

  const int bid = (int)blockIdx.x;               // 0..1535
  const int lid = (bid & 7) * 192 + (bid >> 3);  // bijective XCD chunking
  const int bh = lid >> 5;                       // 0..47
  const int qt = lid & 31;                       // 0..31
  const int b = bh / HH;
  const int qbase = qt * 64 + w * 16;

  const u16t* qh = Qh + (size_t)bh * SS * 64;
  const u16t* kh = Kh + (size_t)bh * SS * 64;
  const u16t* vh = Vh + (size_t)bh * SS * 64;

  // Q fragments (B operand): bq_[ks] = Q[qbase+lq][ks*32 + {4lg..+3, 16+4lg..+3}]
  FragU bq_[2];
  {
    const u16t* qp = qh + (size_t)(qbase + lq) * 64;
#pragma unroll
    for (int ks = 0; ks < 2; ++ks) {
      bq_[ks].h[0] = *(const ushort4*)(qp + ks * 32 + 4 * lg);
      bq_[ks].h[1] = *(const ushort4*)(qp + ks * 32 + 4 * lg + 16);
    }
  }

  // packed mask row for this lane's q-row
  const u32t* mrow = pm + ((size_t)b * SS + qbase + lq) * 64;

  // exp2-folded constants: p' = exp2(acc*SC - B4)  ==  exp((acc/8) - 4)
  const float SC = 0.125f * 1.44269504f;
  const float B4 = 4.0f * 1.44269504f;

#define STAGE_K(kt_, buf_)                                                        \
  _Pragma("unroll")                                                               \
  for (int j = 0; j < 2; ++j) {                                                   \
    const int rr = (w * 2 + j) * 8 + (l >> 3);                                    \
    const u16t* gsrc = kh + (size_t)((kt_) * 64 + rr) * 64 + ((l & 7) ^ (l >> 3)) * 8; \
    __builtin_amdgcn_global_load_lds(                                             \
        (const __attribute__((address_space(1))) void*)gsrc,                      \
        (__attribute__((address_space(3))) void*)(&Kl[buf_][(w * 2 + j) * 512]),  \
        16, 0, 0);                                                                \
  }

#define STAGE_V(kt_, buf_)                                                        \
  _Pragma("unroll")                                                               \
  for (int j = 0; j < 2; ++j) {                                                   \
    const int dv = (w * 2 + j) * 8 + (l >> 3);                                    \
    const u16t* gsrc = vh + (size_t)dv * SS + (kt_) * 64 + ((l & 7) ^ (l >> 3)) * 8; \
    __builtin_amdgcn_global_load_lds(                                             \
        (const __attribute__((address_space(1))) void*)gsrc,                      \
        (__attribute__((address_space(3))) void*)(&Vt[buf_][(w * 2 + j) * 512]),  \
        16, 0, 0);                                                                \
  }

  // one 16q x 16k score chunk: 2 MFMA over dh=64
#define QKT_CHUNK(nt_, buf_, accv)                                                \
  {                                                                               \
    const int krow = (nt_) * 16 + lq;                                             \
    const int xr = (krow & 7) * 8;                                                \
    _Pragma("unroll")                                                             \
    for (int r = 0; r < 4; ++r) (accv)[r] = 0.f;                                  \
    _Pragma("unroll")                                                             \
    for (int ks = 0; ks < 2; ++ks) {                                              \
      FragU ak;                                                                   \
      ak.h[0] = *(const ushort4*)&Kl[buf_][krow * 64 + ((ks * 32 + 4 * lg) ^ xr)];\
      ak.h[1] = *(const ushort4*)&Kl[buf_][krow * 64 + ((ks * 32 + 4 * lg + 16) ^ xr)]; \
      (accv) = __builtin_amdgcn_mfma_f32_16x16x32_bf16(ak.v, bq_[ks].v, (accv), 0, 0, 0); \
    }                                                                             \
  }

  float ssum = 0.f;

  // prologue: K(0) into buf 0
  STAGE_K(0, 0)
  asm volatile("s_waitcnt vmcnt(0)" ::: "memory");
  __syncthreads();

  // ---------------- sweep 1: row exp-sums (fixed max, no serial chain) ----------------
  for (int kt = 0; kt < 32; ++kt) {
    const int cur = kt & 1;
    if (kt < 31) { STAGE_K(kt + 1, cur ^ 1) }
    else         { STAGE_K(0, cur ^ 1) STAGE_V(0, cur ^ 1) }   // prefetch sweep-2 tile 0
    const uint2 mw = *(const uint2*)(mrow + kt * 2);
#pragma unroll
    for (int nt = 0; nt < 4; ++nt) {
      f32x4 a;
      QKT_CHUNK(nt, cur, a)
      const u32t word = (nt < 2) ? mw.x : mw.y;
      const int sh = 16 * (nt & 1) + 4 * lg;
#pragma unroll
      for (int r = 0; r < 4; ++r) {
        float s = fmaf(a[r], SC, -B4);
        if ((word >> (sh + r)) & 1) s = -1.0e9f;
        ssum += __builtin_exp2f(s);
      }
    }
    asm volatile("s_waitcnt vmcnt(0)" ::: "memory");
    __syncthreads();
  }

  // reduce over the 4 lg-slices of each q-row
  ssum += __shfl_xor(ssum, 16);
  ssum += __shfl_xor(ssum, 32);
  const float inv = 1.0f / ssum;

  f32x4 acco[4];
#pragma unroll
  for (int i = 0; i < 4; ++i)
#pragma unroll
    for (int r = 0; r < 4; ++r) acco[i][r] = 0.f;

  const size_t prow = ((size_t)bh * SS + qbase + lq) * SS;

  // ---------------- sweep 2: recompute -> probs (nontemporal) + PV ----------------
  for (int kt = 0; kt < 32; ++kt) {
    const int cur = kt & 1;
    if (kt < 31) { STAGE_K(kt + 1, cur ^ 1) STAGE_V(kt + 1, cur ^ 1) }
    const uint2 mw = *(const uint2*)(mrow + kt * 2);

    f32x4 sc[4];
#pragma unroll
    for (int nt = 0; nt < 4; ++nt) {
      f32x4 a;
      QKT_CHUNK(nt, cur, a)
      const u32t word = (nt < 2) ? mw.x : mw.y;
      const int sh = 16 * (nt & 1) + 4 * lg;
#pragma unroll
      for (int r = 0; r < 4; ++r) {
        float s = fmaf(a[r], SC, -B4);
        if ((word >> (sh + r)) & 1) s = -1.0e9f;
        sc[nt][r] = __builtin_exp2f(s) * inv;
      }
    }

    // probs: lane writes 4 consecutive floats per chunk (16 B) — ext-vector store
#pragma unroll
    for (int nt = 0; nt < 4; ++nt) {
      __builtin_nontemporal_store(sc[nt], (f32x4*)(probs + prow + kt * 64 + nt * 16 + 4 * lg));
    }

    // P as PV A-operand (same k-map as QK^T acc): pf[c] covers k = c*32 .. +31
    FragU pf[2];
#pragma unroll
    for (int c = 0; c < 2; ++c) {
      pf[c].g[0] = pkbf2(sc[2 * c][0],     sc[2 * c][1]);
      pf[c].g[1] = pkbf2(sc[2 * c][2],     sc[2 * c][3]);
      pf[c].g[2] = pkbf2(sc[2 * c + 1][0], sc[2 * c + 1][1]);
      pf[c].g[3] = pkbf2(sc[2 * c + 1][2], sc[2 * c + 1][3]);
    }

    // PV: O[q][dh] += P(16x64) @ V(64x64); B = V from Vt (V^T layout [dh][k])
    __builtin_amdgcn_s_setprio(1);
#pragma unroll
    for (int c = 0; c < 2; ++c) {
#pragma unroll
      for (int n0 = 0; n0 < 4; ++n0) {
        const int dv = n0 * 16 + lq;
        const int xv = (dv & 7) * 8;
        FragU bv;
        bv.h[0] = *(const ushort4*)&Vt[cur][dv * 64 + ((c * 32 + 4 * lg) ^ xv)];
        bv.h[1] = *(const ushort4*)&Vt[cur][dv * 64 + ((c * 32 + 4 * lg + 16) ^ xv)];
        acco[n0] = __builtin_amdgcn_mfma_f32_16x16x32_bf16(pf[c].v, bv.v, acco[n0], 0, 0, 0);
      }
    }
    __builtin_amdgcn_s_setprio(0);

    asm volatile("s_waitcnt vmcnt(0)" ::: "memory");
    __syncthreads();
  }

  // ctx epilogue: O[q = qbase+4lg+r][d = h*64 + n0*16 + lq]
  {
    const int h = bh % HH;
    const size_t cbase = (size_t)(b * SS + qbase) * DD + h * 64;
#pragma unroll
    for (int n0 = 0; n0 < 4; ++n0)
#pragma unroll
      for (int r = 0; r < 4; ++r)
        ctx[cbase + (size_t)(4 * lg + r) * DD + n0 * 16 + lq] = acco[n0][r];
  }
#undef STAGE_K
#undef STAGE_V
#undef QKT_CHUNK
}

extern "C" void kernel_launch(void* const* d_in, const int* in_sizes, int n_in,
                              void* d_out, int out_size, void* d_ws, size_t ws_size,
                              hipStream_t stream)
{
  const float* q   = (const float*)d_in[0];
  const float* k   = (const float*)d_in[1];
  const float* v   = (const float*)d_in[2];
  const void*  msk = d_in[3];
  const float* Wq  = (const float*)d_in[4];
  const float* bq  = (const float*)d_in[5];
  const float* Wk  = (const float*)d_in[6];
  const float* bk  = (const float*)d_in[7];
  const float* Wv  = (const float*)d_in[8];
  const float* bv  = (const float*)d_in[9];
  (void)in_sizes; (void)n_in; (void)out_size; (void)ws_size;

  const size_t NE = (size_t)BB * SS * DD;
  u16t* Qb = (u16t*)d_ws;
  u16t* Kb = Qb + NE;
  u16t* Vb = Kb + NE;
  u32t* pm = (u32t*)(Vb + NE);                // 8192 rows x 64 words = 2 MB
  int* flag = (int*)(pm + (size_t)BB * SS * 64);

  float* ctx   = (float*)d_out;
  float* probs = ctx + NE;

  detect_kernel<<<1, 256, 0, stream>>>((const u32t*)msk, flag);
  mask_pack_kernel<<<2048, 256, 0, stream>>>(msk, flag, pm);

  dim3 pg(BB * SS / 64, DD / 128);
  proj_qk_kernel<<<pg, 256, 0, stream>>>(q, Wq, bq, Qb);
  proj_qk_kernel<<<pg, 256, 0, stream>>>(k, Wk, bk, Kb);
  proj_v_kernel <<<pg, 256, 0, stream>>>(v, Wv, bv, Vb);

  attn_kernel<<<dim3(1536), 256, 0, stream>>>(Qb, Kb, Vb, pm, ctx, probs);
}

// Round 7
// 415.471 us; speedup vs baseline: 2.2485x; 1.0335x over previous
//
#include <hip/hip_runtime.h>
#include <hip/hip_bf16.h>

// B=4, S=2048, D=768, H=12, DH=64
// out = [ ctx (B*S*D fp32) | probs (B*H*S*S fp32) ]
#define BB 4
#define SS 2048
#define DD 768
#define HH 12
#define NE 6291456   // BB*SS*DD

typedef unsigned short u16t;
typedef unsigned char  u8t;
typedef unsigned int   u32t;
typedef __attribute__((ext_vector_type(8)))  short bf16x8;
typedef __attribute__((ext_vector_type(4)))  float f32x4;

union FragU { bf16x8 v; ushort4 h[2]; uint4 u; u32t g[4]; };

__device__ __forceinline__ u16t f2bf(float f) {
  union { float fv; u32t u; } x; x.fv = f;
  u32t r = x.u + 0x7FFFu + ((x.u >> 16) & 1u);   // RNE f32 -> bf16
  return (u16t)(r >> 16);
}

__device__ __forceinline__ u32t pkbf2(float a, float b) {  // 2xf32 -> packed bf16x2
  __hip_bfloat162 h2 = __float22bfloat162_rn(make_float2(a, b));
  union { __hip_bfloat162 h; u32t u; } c; c.h = h2;
  return c.u;
}

__device__ __forceinline__ u32t pack4(u32t w) {
  return ((w & 0x01010101u) * 0x01020408u) >> 24;
}
__device__ __forceinline__ u32t pack16b(uint4 v) {
  return pack4(v.x) | (pack4(v.y) << 4) | (pack4(v.z) << 8) | (pack4(v.w) << 12);
}
__device__ __forceinline__ u32t pack_i4(int4 v) {
  return (v.x ? 1u : 0u) | ((v.y ? 1u : 0u) << 1) | ((v.z ? 1u : 0u) << 2) | ((v.w ? 1u : 0u) << 3);
}
__device__ __forceinline__ u32t pack_f4(float4 v) {
  return (v.x != 0.f ? 1u : 0u) | ((v.y != 0.f ? 1u : 0u) << 1) |
         ((v.z != 0.f ? 1u : 0u) << 2) | ((v.w != 0.f ? 1u : 0u) << 3);
}

// ---- mask dtype detector: flag = 0 int32(0/1), 1 bool bytes, 2 float32(0/1) ----
__global__ void detect_kernel(const u32t* __restrict__ mp, int* __restrict__ flag)
{
  __shared__ int s_isb, s_isf;
  if (threadIdx.x == 0) { s_isb = 0; s_isf = 0; }
  __syncthreads();
  int isb = 0, isf = 0;
  for (int i = threadIdx.x; i < 16384; i += 256) {
    u32t v = mp[i];
    if ((v & 0xFF000000u) == 0x3F000000u) isf = 1;
    else if (v & 0xFFFFFF00u) isb = 1;
  }
  if (isb) atomicOr(&s_isb, 1);
  if (isf) atomicOr(&s_isf, 1);
  __syncthreads();
  if (threadIdx.x == 0) *flag = s_isf ? 2 : (s_isb ? 1 : 0);
}

// ---- mask pre-pack: pm[row = b*S+q][c] bit j = mask[b][q][c*32+j]  (2 MB) ----
__global__ __launch_bounds__(256)
void mask_pack_kernel(const void* __restrict__ msk, const int* __restrict__ flagp,
                      u32t* __restrict__ pm)
{
  const int gid = blockIdx.x * 256 + threadIdx.x;   // 0 .. 524287
  const int row = gid >> 6, c = gid & 63;
  const int fmt = *flagp;
  const size_t src = (size_t)(row >> 11) * SS * SS + (size_t)(row & 2047) * SS + c * 32;
  u32t bits;
  if (fmt == 1) {
    const uint4* s = (const uint4*)((const u8t*)msk + src);
    bits = pack16b(s[0]) | (pack16b(s[1]) << 16);
  } else if (fmt == 0) {
    const int4* s = (const int4*)((const int*)msk + src);
    bits = 0;
#pragma unroll
    for (int j = 0; j < 8; ++j) bits |= pack_i4(s[j]) << (j * 4);
  } else {
    const float4* s = (const float4*)((const float*)msk + src);
    bits = 0;
#pragma unroll
    for (int j = 0; j < 8; ++j) bits |= pack_f4(s[j]) << (j * 4);
  }
  pm[(size_t)row * 64 + c] = bits;
}

// ---- X convert: fp32 [8192][768] -> bf16, 3 tensors (grid.y selects) ----
__global__ __launch_bounds__(256)
void cvt_x_kernel(const float* __restrict__ q, const float* __restrict__ k,
                  const float* __restrict__ v, u16t* __restrict__ xb)
{
  const float* src = (blockIdx.y == 0) ? q : (blockIdx.y == 1) ? k : v;
  u16t* dst = xb + (size_t)blockIdx.y * NE;
  const size_t i = ((size_t)blockIdx.x * 256 + threadIdx.x) * 8;
  float4 f0 = *(const float4*)(src + i);
  float4 f1 = *(const float4*)(src + i + 4);
  uint4 o;
  o.x = pkbf2(f0.x, f0.y); o.y = pkbf2(f0.z, f0.w);
  o.z = pkbf2(f1.x, f1.y); o.w = pkbf2(f1.z, f1.w);
  *(uint4*)(dst + i) = o;
}

// ---- W convert+transpose: Wt[n][k] = bf16(W[k][n]); 3 matrices (grid.z) ----
__global__ __launch_bounds__(256)
void cvt_w_kernel(const float* __restrict__ Wq, const float* __restrict__ Wk,
                  const float* __restrict__ Wv, u16t* __restrict__ Wt)
{
  __shared__ u16t T[64 * 72];
  const int t = threadIdx.x;
  const float* W = (blockIdx.z == 0) ? Wq : (blockIdx.z == 1) ? Wk : Wv;
  u16t* wt = Wt + (size_t)blockIdx.z * DD * DD;
  const int n0 = blockIdx.x * 64, k0 = blockIdx.y * 64;
  const int r = t >> 2, cs = (t & 3) * 16;
#pragma unroll
  for (int i = 0; i < 4; ++i) {
    float4 f = *(const float4*)(W + (size_t)(k0 + r) * DD + n0 + cs + i * 4);
    T[(cs + i * 4 + 0) * 72 + r] = f2bf(f.x);
    T[(cs + i * 4 + 1) * 72 + r] = f2bf(f.y);
    T[(cs + i * 4 + 2) * 72 + r] = f2bf(f.z);
    T[(cs + i * 4 + 3) * 72 + r] = f2bf(f.w);
  }
  __syncthreads();
#pragma unroll
  for (int i = 0; i < 2; ++i) {
    uint4 vv = *(const uint4*)&T[r * 72 + cs + i * 8];
    *(uint4*)(wt + (size_t)(n0 + r) * DD + k0 + cs + i * 8) = vv;
  }
}

// ---- proj GEMM core: acc[8] += Xb[m0..+64][:] @ Wt[n0..+128][:]^T ----
// Pure bf16, gload_lds staging (pre-swizzled source, linear LDS dest), dbuf.
// Ab: 2 x [64][64] (8K u16), Bb: 2 x [128][64] (16K u16). 48 KB total.
__device__ __forceinline__ void proj_core(const u16t* __restrict__ Xrow,
    const u16t* __restrict__ Wrow, u16t* __restrict__ Ab, u16t* __restrict__ Bb,
    int t, f32x4 acc[8])
{
  const int w = t >> 6, l = t & 63;
  const int lq = l & 15, lg = l >> 4;
  const int gr = l >> 3;
  const int gc = ((l & 7) ^ (l >> 3)) * 8;

#define PSTAGE_A(kk_, buf_)                                                       \
  _Pragma("unroll")                                                               \
  for (int j = 0; j < 2; ++j) {                                                   \
    const int rr = (w * 2 + j) * 8 + gr;                                          \
    const u16t* gsrc = Xrow + (size_t)rr * DD + (kk_) + gc;                       \
    __builtin_amdgcn_global_load_lds(                                             \
        (const __attribute__((address_space(1))) void*)gsrc,                      \
        (__attribute__((address_space(3))) void*)(Ab + (buf_) * 4096 + (w * 2 + j) * 512), \
        16, 0, 0);                                                                \
  }
#define PSTAGE_B(kk_, buf_)                                                       \
  _Pragma("unroll")                                                               \
  for (int j = 0; j < 4; ++j) {                                                   \
    const int rr = (w * 4 + j) * 8 + gr;                                          \
    const u16t* gsrc = Wrow + (size_t)rr * DD + (kk_) + gc;                       \
    __builtin_amdgcn_global_load_lds(                                             \
        (const __attribute__((address_space(1))) void*)gsrc,                      \
        (__attribute__((address_space(3))) void*)(Bb + (buf_) * 8192 + (w * 4 + j) * 512), \
        16, 0, 0);                                                                \
  }

  PSTAGE_A(0, 0)
  PSTAGE_B(0, 0)
  __syncthreads();

  const int xa = (lq & 7) * 8;
  for (int kki = 0; kki < 12; ++kki) {
    const int buf = kki & 1;
    if (kki < 11) { PSTAGE_A((kki + 1) * 64, buf ^ 1) PSTAGE_B((kki + 1) * 64, buf ^ 1) }
    const int arow = w * 16 + lq;
    FragU af[2];
#pragma unroll
    for (int ks = 0; ks < 2; ++ks) {
      af[ks].h[0] = *(const ushort4*)&Ab[buf * 4096 + arow * 64 + ((ks * 32 + 4 * lg) ^ xa)];
      af[ks].h[1] = *(const ushort4*)&Ab[buf * 4096 + arow * 64 + ((ks * 32 + 4 * lg + 16) ^ xa)];
    }
#pragma unroll
    for (int nt = 0; nt < 8; ++nt) {
      const int brow = nt * 16 + lq;
#pragma unroll
      for (int ks = 0; ks < 2; ++ks) {
        FragU bf;
        bf.h[0] = *(const ushort4*)&Bb[buf * 8192 + brow * 64 + ((ks * 32 + 4 * lg) ^ xa)];
        bf.h[1] = *(const ushort4*)&Bb[buf * 8192 + brow * 64 + ((ks * 32 + 4 * lg + 16) ^ xa)];
        acc[nt] = __builtin_amdgcn_mfma_f32_16x16x32_bf16(af[ks].v, bf.v, acc[nt], 0, 0, 0);
      }
    }
    __syncthreads();
  }
#undef PSTAGE_A
#undef PSTAGE_B
}

// ---- proj Q/K: out layout [b][h][s][64] bf16 ----
__global__ __launch_bounds__(256, 3)
void proj_qk_kernel(const u16t* __restrict__ Xb, const u16t* __restrict__ Wt,
                    const float* __restrict__ bias, u16t* __restrict__ out)
{
  __shared__ u16t Ab[2 * 4096];
  __shared__ u16t Bb[2 * 8192];
  const int t = threadIdx.x;
  const int w = t >> 6, l = t & 63;
  const int lq = l & 15, lg = l >> 4;
  const int m0 = blockIdx.x * 64;
  const int n0 = blockIdx.y * 128;
  const int b = m0 >> 11;

  f32x4 acc[8];
#pragma unroll
  for (int i = 0; i < 8; ++i)
#pragma unroll
    for (int r = 0; r < 4; ++r) acc[i][r] = 0.f;

  proj_core(Xb + (size_t)m0 * DD, Wt + (size_t)n0 * DD, Ab, Bb, t, acc);

#pragma unroll
  for (int nt = 0; nt < 8; ++nt) {
    const int n = n0 + nt * 16 + lq;
    const int h = n >> 6, dh = n & 63;
    const float bb = bias[n];
#pragma unroll
    for (int r = 0; r < 4; ++r) {
      const int s = (m0 & 2047) + w * 16 + 4 * lg + r;
      out[((size_t)(b * HH + h) * SS + s) * 64 + dh] = f2bf(acc[nt][r] + bb);
    }
  }
}

// ---- proj V: out layout [b][h][dh][s] bf16 (transposed via LDS, aliases Bb) ----
__global__ __launch_bounds__(256, 3)
void proj_v_kernel(const u16t* __restrict__ Xb, const u16t* __restrict__ Wt,
                   const float* __restrict__ bias, u16t* __restrict__ out)
{
  __shared__ u16t Ab[2 * 4096];
  __shared__ u16t Bb[2 * 8192];
  const int t = threadIdx.x;
  const int w = t >> 6, l = t & 63;
  const int lq = l & 15, lg = l >> 4;
  const int m0 = blockIdx.x * 64;
  const int n0 = blockIdx.y * 128;
  const int b = m0 >> 11;

  f32x4 acc[8];
#pragma unroll
  for (int i = 0; i < 8; ++i)
#pragma unroll
    for (int r = 0; r < 4; ++r) acc[i][r] = 0.f;

  proj_core(Xb + (size_t)m0 * DD, Wt + (size_t)n0 * DD, Ab, Bb, t, acc);

  u16t* Tl = Bb;   // 128 x 72 = 9216 u16, fits in Bb (16384)
#pragma unroll
  for (int nt = 0; nt < 8; ++nt) {
    const float bb = bias[n0 + nt * 16 + lq];
#pragma unroll
    for (int r = 0; r < 4; ++r)
      Tl[(nt * 16 + lq) * 72 + w * 16 + 4 * lg + r] = f2bf(acc[nt][r] + bb);
  }
  __syncthreads();

  const int rowl = t >> 1;
  const int half = t & 1;
  const int ncol = n0 + rowl;
  const int h = ncol >> 6, dh = ncol & 63;
  const int s = (m0 & 2047) + half * 32;
  u16t* dst = out + ((size_t)(b * HH + h) * 64 + dh) * SS + s;
#pragma unroll
  for (int i = 0; i < 4; ++i) {
    uint4 vv = *(const uint4*)&Tl[rowl * 72 + half * 32 + i * 8];
    *(uint4*)(dst + i * 8) = vv;
  }
}

// ---- fused attention: raw s_barrier + counted vmcnt (T4), 3-buf K/V DMA,
//      depth-2 prefetch, stores never drained in-loop, fixed-max softmax ----
__global__ __launch_bounds__(256, 3)
void attn_kernel(const u16t* __restrict__ Qh, const u16t* __restrict__ Kh,
                 const u16t* __restrict__ Vh, const u32t* __restrict__ pm,
                 float* __restrict__ ctx, float* __restrict__ probs)
{
  __shared__ u16t Kb3[3][64 * 64];   // 24 KB
  __shared__ u16t Vb3[3][64 * 64];   // 24 KB

  const int t = threadIdx.x;
  const int w = t >> 6, l = t & 63;
  const int lq = l & 15, lg = l >> 4;

  const int bid = (int)blockIdx.x;               // 0..1535
  const int lid = (bid & 7) * 192 + (bid >> 3);  // bijective XCD chunking
  const int bh = lid >> 5;                       // 0..47
  const int qt = lid & 31;                       // 0..31
  const int b = bh / HH;
  const int qbase = qt * 64 + w * 16;

  const u16t* qh = Qh + (size_t)bh * SS * 64;
  const u16t* kh = Kh + (size_t)bh * SS * 64;
  const u16t* vh = Vh + (size_t)bh * SS * 64;

  FragU bq_[2];
  {
    const u16t* qp = qh + (size_t)(qbase + lq) * 64;
#pragma unroll
    for (int ks = 0; ks < 2; ++ks) {
      bq_[ks].h[0] = *(const ushort4*)(qp + ks * 32 + 4 * lg);
      bq_[ks].h[1] = *(const ushort4*)(qp + ks * 32 + 4 * lg + 16);
    }
  }

  const u32t* mrow = pm + ((size_t)b * SS + qbase + lq) * 64;

  const float SC = 0.125f * 1.44269504f;
  const float B4 = 4.0f * 1.44269504f;

  const int gr = l >> 3;
  const int gc = ((l & 7) ^ (l >> 3)) * 8;

#define STAGE_K(kt_, buf_)                                                        \
  _Pragma("unroll")                                                               \
  for (int j = 0; j < 2; ++j) {                                                   \
    const int rr = (w * 2 + j) * 8 + gr;                                          \
    const u16t* gsrc = kh + (size_t)((kt_) * 64 + rr) * 64 + gc;                  \
    __builtin_amdgcn_global_load_lds(                                             \
        (const __attribute__((address_space(1))) void*)gsrc,                      \
        (__attribute__((address_space(3))) void*)(&Kb3[buf_][(w * 2 + j) * 512]), \
        16, 0, 0);                                                                \
  }

#define STAGE_V(kt_, buf_)                                                        \
  _Pragma("unroll")                                                               \
  for (int j = 0; j < 2; ++j) {                                                   \
    const int dv = (w * 2 + j) * 8 + gr;                                          \
    const u16t* gsrc = vh + (size_t)dv * SS + (kt_) * 64 + gc;                    \
    __builtin_amdgcn_global_load_lds(                                             \
        (const __attribute__((address_space(1))) void*)gsrc,                      \
        (__attribute__((address_space(3))) void*)(&Vb3[buf_][(w * 2 + j) * 512]), \
        16, 0, 0);                                                                \
  }

#define QKT_CHUNK(nt_, buf_, accv)                                                \
  {                                                                               \
    const int krow = (nt_) * 16 + lq;                                             \
    const int xr = (lq & 7) * 8;                                                  \
    _Pragma("unroll")                                                             \
    for (int r = 0; r < 4; ++r) (accv)[r] = 0.f;                                  \
    _Pragma("unroll")                                                             \
    for (int ks = 0; ks < 2; ++ks) {                                              \
      FragU ak;                                                                   \
      ak.h[0] = *(const ushort4*)&Kb3[buf_][krow * 64 + ((ks * 32 + 4 * lg) ^ xr)]; \
      ak.h[1] = *(const ushort4*)&Kb3[buf_][krow * 64 + ((ks * 32 + 4 * lg + 16) ^ xr)]; \
      (accv) = __builtin_amdgcn_mfma_f32_16x16x32_bf16(ak.v, bq_[ks].v, (accv), 0, 0, 0); \
    }                                                                             \
  }

  float ssum = 0.f;

  // ---------------- sweep 1: K-only, 3-buf, depth-2 prefetch ----------------
  STAGE_K(0, 0)
  STAGE_K(1, 1)
  for (int kt = 0; kt < 32; ++kt) {
    if (kt == 31) { asm volatile("s_waitcnt vmcnt(0)" ::: "memory"); }
    else          { asm volatile("s_waitcnt vmcnt(2)" ::: "memory"); }
    __builtin_amdgcn_s_barrier();
    if (kt < 30) { STAGE_K(kt + 2, (kt + 2) % 3) }
    const int buf = kt % 3;
    const uint2 mw = *(const uint2*)(mrow + kt * 2);
#pragma unroll
    for (int nt = 0; nt < 4; ++nt) {
      f32x4 a;
      QKT_CHUNK(nt, buf, a)
      const u32t word = (nt < 2) ? mw.x : mw.y;
      const int sh = 16 * (nt & 1) + 4 * lg;
#pragma unroll
      for (int r = 0; r < 4; ++r) {
        float s = fmaf(a[r], SC, -B4);
        if ((word >> (sh + r)) & 1) s = -1.0e9f;
        ssum += __builtin_exp2f(s);
      }
    }
  }

  ssum += __shfl_xor(ssum, 16);
  ssum += __shfl_xor(ssum, 32);
  const float inv = 1.0f / ssum;

  f32x4 acco[4];
#pragma unroll
  for (int i = 0; i < 4; ++i)
#pragma unroll
    for (int r = 0; r < 4; ++r) acco[i][r] = 0.f;

  const size_t prow = ((size_t)bh * SS + qbase + lq) * SS;

  // ---------------- sweep 2: K+V 3-buf depth-2; stores stay in flight ----------------
  __builtin_amdgcn_s_barrier();          // all waves done reading sweep-1 bufs
  STAGE_K(0, 0) STAGE_V(0, 0)
  STAGE_K(1, 1) STAGE_V(1, 1)

  for (int kt = 0; kt < 32; ++kt) {
    if (kt == 0)                  { asm volatile("s_waitcnt vmcnt(4)"  ::: "memory"); }
    else if (kt == 1 || kt == 31) { asm volatile("s_waitcnt vmcnt(8)"  ::: "memory"); }
    else                          { asm volatile("s_waitcnt vmcnt(12)" ::: "memory"); }
    __builtin_amdgcn_s_barrier();
    if (kt < 30) { STAGE_K(kt + 2, (kt + 2) % 3) STAGE_V(kt + 2, (kt + 2) % 3) }
    const int buf = kt % 3;
    const uint2 mw = *(const uint2*)(mrow + kt * 2);

    f32x4 sc[4];
#pragma unroll
    for (int nt = 0; nt < 4; ++nt) {
      f32x4 a;
      QKT_CHUNK(nt, buf, a)
      const u32t word = (nt < 2) ? mw.x : mw.y;
      const int sh = 16 * (nt & 1) + 4 * lg;
#pragma unroll
      for (int r = 0; r < 4; ++r) {
        float s = fmaf(a[r], SC, -B4);
        if ((word >> (sh + r)) & 1) s = -1.0e9f;
        sc[nt][r] = __builtin_exp2f(s) * inv;
      }
    }

#pragma unroll
    for (int nt = 0; nt < 4; ++nt) {
      __builtin_nontemporal_store(sc[nt], (f32x4*)(probs + prow + kt * 64 + nt * 16 + 4 * lg));
    }

    FragU pf[2];
#pragma unroll
    for (int c = 0; c < 2; ++c) {
      pf[c].g[0] = pkbf2(sc[2 * c][0],     sc[2 * c][1]);
      pf[c].g[1] = pkbf2(sc[2 * c][2],     sc[2 * c][3]);
      pf[c].g[2] = pkbf2(sc[2 * c + 1][0], sc[2 * c + 1][1]);
      pf[c].g[3] = pkbf2(sc[2 * c + 1][2], sc[2 * c + 1][3]);
    }

    __builtin_amdgcn_s_setprio(1);
#pragma unroll
    for (int c = 0; c < 2; ++c) {
#pragma unroll
      for (int n0 = 0; n0 < 4; ++n0) {
        const int dv = n0 * 16 + lq;
        const int xv = (lq & 7) * 8;
        FragU bv;
        bv.h[0] = *(const ushort4*)&Vb3[buf][dv * 64 + ((c * 32 + 4 * lg) ^ xv)];
        bv.h[1] = *(const ushort4*)&Vb3[buf][dv * 64 + ((c * 32 + 4 * lg + 16) ^ xv)];
        acco[n0] = __builtin_amdgcn_mfma_f32_16x16x32_bf16(pf[c].v, bv.v, acco[n0], 0, 0, 0);
      }
    }
    __builtin_amdgcn_s_setprio(0);
  }

  // ctx epilogue: O[q = qbase+4lg+r][d = h*64 + n0*16 + lq]
  {
    const int h = bh % HH;
    const size_t cbase = (size_t)(b * SS + qbase) * DD + h * 64;
#pragma unroll
    for (int n0 = 0; n0 < 4; ++n0)
#pragma unroll
      for (int r = 0; r < 4; ++r)
        ctx[cbase + (size_t)(4 * lg + r) * DD + n0 * 16 + lq] = acco[n0][r];
  }
#undef STAGE_K
#undef STAGE_V
#undef QKT_CHUNK
}

extern "C" void kernel_launch(void* const* d_in, const int* in_sizes, int n_in,
                              void* d_out, int out_size, void* d_ws, size_t ws_size,
                              hipStream_t stream)
{
  const float* q   = (const float*)d_in[0];
  const float* k   = (const float*)d_in[1];
  const float* v   = (const float*)d_in[2];
  const void*  msk = d_in[3];
  const float* Wq  = (const float*)d_in[4];
  const float* bq  = (const float*)d_in[5];
  const float* Wk  = (const float*)d_in[6];
  const float* bk  = (const float*)d_in[7];
  const float* Wv  = (const float*)d_in[8];
  const float* bv  = (const float*)d_in[9];
  (void)in_sizes; (void)n_in; (void)out_size; (void)ws_size;

  u16t* Qb = (u16t*)d_ws;
  u16t* Kb = Qb + NE;
  u16t* Vb = Kb + NE;
  u32t* pm = (u32t*)(Vb + NE);                // 8192 rows x 64 words = 2 MB
  int* flag = (int*)(pm + (size_t)BB * SS * 64);

  float* ctx   = (float*)d_out;
  float* probs = ctx + NE;

  // scratch inside probs region (fully overwritten by attn afterwards)
  u16t* Xb = (u16t*)probs;                    // 3 x NE bf16 = 37.7 MB
  u16t* Wt = Xb + (size_t)3 * NE;             // 3 x 768x768 bf16 = 3.5 MB

  detect_kernel<<<1, 256, 0, stream>>>((const u32t*)msk, flag);
  mask_pack_kernel<<<2048, 256, 0, stream>>>(msk, flag, pm);

  cvt_x_kernel<<<dim3(3072, 3), 256, 0, stream>>>(q, k, v, Xb);
  cvt_w_kernel<<<dim3(12, 12, 3), 256, 0, stream>>>(Wq, Wk, Wv, Wt);

  dim3 pg(BB * SS / 64, DD / 128);
  proj_qk_kernel<<<pg, 256, 0, stream>>>(Xb,          Wt,               bq, Qb);
  proj_qk_kernel<<<pg, 256, 0, stream>>>(Xb + NE,     Wt + DD * DD,     bk, Kb);
  proj_v_kernel <<<pg, 256, 0, stream>>>(Xb + 2 * NE, Wt + 2 * DD * DD, bv, Vb);

  attn_kernel<<<dim3(1536), 256, 0, stream>>>(Qb, Kb, Vb, pm, ctx, probs);
}

// Round 8
// 377.290 us; speedup vs baseline: 2.4760x; 1.1012x over previous
//
#include <hip/hip_runtime.h>
#include <hip/hip_bf16.h>

// B=4, S=2048, D=768, H=12, DH=64
// out = [ ctx (B*S*D fp32) | probs (B*H*S*S fp32) ]
#define BB 4
#define SS 2048
#define DD 768
#define HH 12
#define NE 6291456   // BB*SS*DD

typedef unsigned short u16t;
typedef unsigned char  u8t;
typedef unsigned int   u32t;
typedef __attribute__((ext_vector_type(8)))  short bf16x8;
typedef __attribute__((ext_vector_type(4)))  float f32x4;

union FragU { bf16x8 v; ushort4 h[2]; uint4 u; u32t g[4]; };

__device__ __forceinline__ u16t f2bf(float f) {
  union { float fv; u32t u; } x; x.fv = f;
  u32t r = x.u + 0x7FFFu + ((x.u >> 16) & 1u);   // RNE f32 -> bf16
  return (u16t)(r >> 16);
}

__device__ __forceinline__ u32t pkbf2(float a, float b) {  // 2xf32 -> packed bf16x2
  __hip_bfloat162 h2 = __float22bfloat162_rn(make_float2(a, b));
  union { __hip_bfloat162 h; u32t u; } c; c.h = h2;
  return c.u;
}

__device__ __forceinline__ u32t pack4(u32t w) {
  return ((w & 0x01010101u) * 0x01020408u) >> 24;
}
__device__ __forceinline__ u32t pack16b(uint4 v) {
  return pack4(v.x) | (pack4(v.y) << 4) | (pack4(v.z) << 8) | (pack4(v.w) << 12);
}
__device__ __forceinline__ u32t pack_i4(int4 v) {
  return (v.x ? 1u : 0u) | ((v.y ? 1u : 0u) << 1) | ((v.z ? 1u : 0u) << 2) | ((v.w ? 1u : 0u) << 3);
}
__device__ __forceinline__ u32t pack_f4(float4 v) {
  return (v.x != 0.f ? 1u : 0u) | ((v.y != 0.f ? 1u : 0u) << 1) |
         ((v.z != 0.f ? 1u : 0u) << 2) | ((v.w != 0.f ? 1u : 0u) << 3);
}

// ---- mask dtype detector: flag = 0 int32(0/1), 1 bool bytes, 2 float32(0/1) ----
__global__ void detect_kernel(const u32t* __restrict__ mp, int* __restrict__ flag)
{
  __shared__ int s_isb, s_isf;
  if (threadIdx.x == 0) { s_isb = 0; s_isf = 0; }
  __syncthreads();
  int isb = 0, isf = 0;
  for (int i = threadIdx.x; i < 16384; i += 256) {
    u32t v = mp[i];
    if ((v & 0xFF000000u) == 0x3F000000u) isf = 1;
    else if (v & 0xFFFFFF00u) isb = 1;
  }
  if (isb) atomicOr(&s_isb, 1);
  if (isf) atomicOr(&s_isf, 1);
  __syncthreads();
  if (threadIdx.x == 0) *flag = s_isf ? 2 : (s_isb ? 1 : 0);
}

// ---- mask pre-pack: pm[row = b*S+q][c] bit j = mask[b][q][c*32+j]  (2 MB) ----
__global__ __launch_bounds__(256)
void mask_pack_kernel(const void* __restrict__ msk, const int* __restrict__ flagp,
                      u32t* __restrict__ pm)
{
  const int gid = blockIdx.x * 256 + threadIdx.x;   // 0 .. 524287
  const int row = gid >> 6, c = gid & 63;
  const int fmt = *flagp;
  const size_t src = (size_t)(row >> 11) * SS * SS + (size_t)(row & 2047) * SS + c * 32;
  u32t bits;
  if (fmt == 1) {
    const uint4* s = (const uint4*)((const u8t*)msk + src);
    bits = pack16b(s[0]) | (pack16b(s[1]) << 16);
  } else if (fmt == 0) {
    const int4* s = (const int4*)((const int*)msk + src);
    bits = 0;
#pragma unroll
    for (int j = 0; j < 8; ++j) bits |= pack_i4(s[j]) << (j * 4);
  } else {
    const float4* s = (const float4*)((const float*)msk + src);
    bits = 0;
#pragma unroll
    for (int j = 0; j < 8; ++j) bits |= pack_f4(s[j]) << (j * 4);
  }
  pm[(size_t)row * 64 + c] = bits;
}

// ---- X convert: fp32 [8192][768] -> bf16, 3 tensors (grid.y selects) ----
__global__ __launch_bounds__(256)
void cvt_x_kernel(const float* __restrict__ q, const float* __restrict__ k,
                  const float* __restrict__ v, u16t* __restrict__ xb)
{
  const float* src = (blockIdx.y == 0) ? q : (blockIdx.y == 1) ? k : v;
  u16t* dst = xb + (size_t)blockIdx.y * NE;
  const size_t i = ((size_t)blockIdx.x * 256 + threadIdx.x) * 8;
  float4 f0 = *(const float4*)(src + i);
  float4 f1 = *(const float4*)(src + i + 4);
  uint4 o;
  o.x = pkbf2(f0.x, f0.y); o.y = pkbf2(f0.z, f0.w);
  o.z = pkbf2(f1.x, f1.y); o.w = pkbf2(f1.z, f1.w);
  *(uint4*)(dst + i) = o;
}

// ---- W convert+transpose: Wt[n][k] = bf16(W[k][n]); 3 matrices (grid.z) ----
__global__ __launch_bounds__(256)
void cvt_w_kernel(const float* __restrict__ Wq, const float* __restrict__ Wk,
                  const float* __restrict__ Wv, u16t* __restrict__ Wt)
{
  __shared__ u16t T[64 * 72];
  const int t = threadIdx.x;
  const float* W = (blockIdx.z == 0) ? Wq : (blockIdx.z == 1) ? Wk : Wv;
  u16t* wt = Wt + (size_t)blockIdx.z * DD * DD;
  const int n0 = blockIdx.x * 64, k0 = blockIdx.y * 64;
  const int r = t >> 2, cs = (t & 3) * 16;
#pragma unroll
  for (int i = 0; i < 4; ++i) {
    float4 f = *(const float4*)(W + (size_t)(k0 + r) * DD + n0 + cs + i * 4);
    T[(cs + i * 4 + 0) * 72 + r] = f2bf(f.x);
    T[(cs + i * 4 + 1) * 72 + r] = f2bf(f.y);
    T[(cs + i * 4 + 2) * 72 + r] = f2bf(f.z);
    T[(cs + i * 4 + 3) * 72 + r] = f2bf(f.w);
  }
  __syncthreads();
#pragma unroll
  for (int i = 0; i < 2; ++i) {
    uint4 vv = *(const uint4*)&T[r * 72 + cs + i * 8];
    *(uint4*)(wt + (size_t)(n0 + r) * DD + k0 + cs + i * 8) = vv;
  }
}

// ---- proj GEMM core: acc[8] += Xb[m0..+64][:] @ Wt[n0..+128][:]^T ----
__device__ __forceinline__ void proj_core(const u16t* __restrict__ Xrow,
    const u16t* __restrict__ Wrow, u16t* __restrict__ Ab, u16t* __restrict__ Bb,
    int t, f32x4 acc[8])
{
  const int w = t >> 6, l = t & 63;
  const int lq = l & 15, lg = l >> 4;
  const int gr = l >> 3;
  const int gc = ((l & 7) ^ (l >> 3)) * 8;

#define PSTAGE_A(kk_, buf_)                                                       \
  _Pragma("unroll")                                                               \
  for (int j = 0; j < 2; ++j) {                                                   \
    const int rr = (w * 2 + j) * 8 + gr;                                          \
    const u16t* gsrc = Xrow + (size_t)rr * DD + (kk_) + gc;                       \
    __builtin_amdgcn_global_load_lds(                                             \
        (const __attribute__((address_space(1))) void*)gsrc,                      \
        (__attribute__((address_space(3))) void*)(Ab + (buf_) * 4096 + (w * 2 + j) * 512), \
        16, 0, 0);                                                                \
  }
#define PSTAGE_B(kk_, buf_)                                                       \
  _Pragma("unroll")                                                               \
  for (int j = 0; j < 4; ++j) {                                                   \
    const int rr = (w * 4 + j) * 8 + gr;                                          \
    const u16t* gsrc = Wrow + (size_t)rr * DD + (kk_) + gc;                       \
    __builtin_amdgcn_global_load_lds(                                             \
        (const __attribute__((address_space(1))) void*)gsrc,                      \
        (__attribute__((address_space(3))) void*)(Bb + (buf_) * 8192 + (w * 4 + j) * 512), \
        16, 0, 0);                                                                \
  }

  PSTAGE_A(0, 0)
  PSTAGE_B(0, 0)
  __syncthreads();

  const int xa = (lq & 7) * 8;
  for (int kki = 0; kki < 12; ++kki) {
    const int buf = kki & 1;
    if (kki < 11) { PSTAGE_A((kki + 1) * 64, buf ^ 1) PSTAGE_B((kki + 1) * 64, buf ^ 1) }
    const int arow = w * 16 + lq;
    FragU af[2];
#pragma unroll
    for (int ks = 0; ks < 2; ++ks) {
      af[ks].h[0] = *(const ushort4*)&Ab[buf * 4096 + arow * 64 + ((ks * 32 + 4 * lg) ^ xa)];
      af[ks].h[1] = *(const ushort4*)&Ab[buf * 4096 + arow * 64 + ((ks * 32 + 4 * lg + 16) ^ xa)];
    }
#pragma unroll
    for (int nt = 0; nt < 8; ++nt) {
      const int brow = nt * 16 + lq;
#pragma unroll
      for (int ks = 0; ks < 2; ++ks) {
        FragU bf;
        bf.h[0] = *(const ushort4*)&Bb[buf * 8192 + brow * 64 + ((ks * 32 + 4 * lg) ^ xa)];
        bf.h[1] = *(const ushort4*)&Bb[buf * 8192 + brow * 64 + ((ks * 32 + 4 * lg + 16) ^ xa)];
        acc[nt] = __builtin_amdgcn_mfma_f32_16x16x32_bf16(af[ks].v, bf.v, acc[nt], 0, 0, 0);
      }
    }
    __syncthreads();
  }
#undef PSTAGE_A
#undef PSTAGE_B
}

// ---- merged projections: z=0 Q, z=1 K (both [b][h][s][64]); z=2 V ([b][h][dh][s]) ----
__global__ __launch_bounds__(256, 3)
void proj_all_kernel(const u16t* __restrict__ Xb, const u16t* __restrict__ Wt,
                     const float* __restrict__ bq, const float* __restrict__ bk,
                     const float* __restrict__ bv,
                     u16t* __restrict__ Qb, u16t* __restrict__ Kb, u16t* __restrict__ Vb)
{
  __shared__ u16t Ab[2 * 4096];
  __shared__ u16t Bb[2 * 8192];
  const int t = threadIdx.x;
  const int w = t >> 6, l = t & 63;
  const int lq = l & 15, lg = l >> 4;
  const int m0 = blockIdx.x * 64;
  const int n0 = blockIdx.y * 128;
  const int z = blockIdx.z;
  const int b = m0 >> 11;

  const float* bias = (z == 0) ? bq : (z == 1) ? bk : bv;
  u16t* out = (z == 0) ? Qb : (z == 1) ? Kb : Vb;

  f32x4 acc[8];
#pragma unroll
  for (int i = 0; i < 8; ++i)
#pragma unroll
    for (int r = 0; r < 4; ++r) acc[i][r] = 0.f;

  proj_core(Xb + (size_t)z * NE + (size_t)m0 * DD,
            Wt + (size_t)z * DD * DD + (size_t)n0 * DD, Ab, Bb, t, acc);

  if (z < 2) {
#pragma unroll
    for (int nt = 0; nt < 8; ++nt) {
      const int n = n0 + nt * 16 + lq;
      const int h = n >> 6, dh = n & 63;
      const float bb = bias[n];
#pragma unroll
      for (int r = 0; r < 4; ++r) {
        const int s = (m0 & 2047) + w * 16 + 4 * lg + r;
        out[((size_t)(b * HH + h) * SS + s) * 64 + dh] = f2bf(acc[nt][r] + bb);
      }
    }
  } else {
    u16t* Tl = Bb;   // 128 x 72 = 9216 u16, fits in Bb
#pragma unroll
    for (int nt = 0; nt < 8; ++nt) {
      const float bb = bias[n0 + nt * 16 + lq];
#pragma unroll
      for (int r = 0; r < 4; ++r)
        Tl[(nt * 16 + lq) * 72 + w * 16 + 4 * lg + r] = f2bf(acc[nt][r] + bb);
    }
    __syncthreads();
    const int rowl = t >> 1;
    const int half = t & 1;
    const int ncol = n0 + rowl;
    const int h = ncol >> 6, dh = ncol & 63;
    const int s = (m0 & 2047) + half * 32;
    u16t* dst = out + ((size_t)(b * HH + h) * 64 + dh) * SS + s;
#pragma unroll
    for (int i = 0; i < 4; ++i) {
      uint4 vv = *(const uint4*)&Tl[rowl * 72 + half * 32 + i * 8];
      *(uint4*)(dst + i * 8) = vv;
    }
  }
}

// ---- fused attention: counted vmcnt, reg-prefetched masks (depth 2), 3-buf K/V DMA ----
__global__ __launch_bounds__(256, 3)
void attn_kernel(const u16t* __restrict__ Qh, const u16t* __restrict__ Kh,
                 const u16t* __restrict__ Vh, const u32t* __restrict__ pm,
                 float* __restrict__ ctx, float* __restrict__ probs)
{
  __shared__ u16t Kb3[3][64 * 64];   // 24 KB
  __shared__ u16t Vb3[3][64 * 64];   // 24 KB

  const int t = threadIdx.x;
  const int w = t >> 6, l = t & 63;
  const int lq = l & 15, lg = l >> 4;

  const int bid = (int)blockIdx.x;               // 0..1535
  const int lid = (bid & 7) * 192 + (bid >> 3);  // bijective XCD chunking
  const int bh = lid >> 5;                       // 0..47
  const int qt = lid & 31;                       // 0..31
  const int b = bh / HH;
  const int qbase = qt * 64 + w * 16;

  const u16t* qh = Qh + (size_t)bh * SS * 64;
  const u16t* kh = Kh + (size_t)bh * SS * 64;
  const u16t* vh = Vh + (size_t)bh * SS * 64;

  FragU bq_[2];
  {
    const u16t* qp = qh + (size_t)(qbase + lq) * 64;
#pragma unroll
    for (int ks = 0; ks < 2; ++ks) {
      bq_[ks].h[0] = *(const ushort4*)(qp + ks * 32 + 4 * lg);
      bq_[ks].h[1] = *(const ushort4*)(qp + ks * 32 + 4 * lg + 16);
    }
  }

  const u32t* mrow = pm + ((size_t)b * SS + qbase + lq) * 64;

  const float SC = 0.125f * 1.44269504f;
  const float B4 = 4.0f * 1.44269504f;

  const int gr = l >> 3;
  const int gc = ((l & 7) ^ (l >> 3)) * 8;

#define STAGE_K(kt_, buf_)                                                        \
  _Pragma("unroll")                                                               \
  for (int j = 0; j < 2; ++j) {                                                   \
    const int rr = (w * 2 + j) * 8 + gr;                                          \
    const u16t* gsrc = kh + (size_t)((kt_) * 64 + rr) * 64 + gc;                  \
    __builtin_amdgcn_global_load_lds(                                             \
        (const __attribute__((address_space(1))) void*)gsrc,                      \
        (__attribute__((address_space(3))) void*)(&Kb3[buf_][(w * 2 + j) * 512]), \
        16, 0, 0);                                                                \
  }

#define STAGE_V(kt_, buf_)                                                        \
  _Pragma("unroll")                                                               \
  for (int j = 0; j < 2; ++j) {                                                   \
    const int dv = (w * 2 + j) * 8 + gr;                                          \
    const u16t* gsrc = vh + (size_t)dv * SS + (kt_) * 64 + gc;                    \
    __builtin_amdgcn_global_load_lds(                                             \
        (const __attribute__((address_space(1))) void*)gsrc,                      \
        (__attribute__((address_space(3))) void*)(&Vb3[buf_][(w * 2 + j) * 512]), \
        16, 0, 0);                                                                \
  }

#define QKT_CHUNK(nt_, buf_, accv)                                                \
  {                                                                               \
    const int krow = (nt_) * 16 + lq;                                             \
    const int xr = (lq & 7) * 8;                                                  \
    _Pragma("unroll")                                                             \
    for (int r = 0; r < 4; ++r) (accv)[r] = 0.f;                                  \
    _Pragma("unroll")                                                             \
    for (int ks = 0; ks < 2; ++ks) {                                              \
      FragU ak;                                                                   \
      ak.h[0] = *(const ushort4*)&Kb3[buf_][krow * 64 + ((ks * 32 + 4 * lg) ^ xr)]; \
      ak.h[1] = *(const ushort4*)&Kb3[buf_][krow * 64 + ((ks * 32 + 4 * lg + 16) ^ xr)]; \
      (accv) = __builtin_amdgcn_mfma_f32_16x16x32_bf16(ak.v, bq_[ks].v, (accv), 0, 0, 0); \
    }                                                                             \
  }

  // sweep-1 per-tile compute (no VMEM)
#define COMPUTE1(buf_, mw_)                                                       \
  {                                                                               \
    _Pragma("unroll")                                                             \
    for (int nt = 0; nt < 4; ++nt) {                                              \
      f32x4 a;                                                                    \
      QKT_CHUNK(nt, buf_, a)                                                      \
      const u32t word = (nt < 2) ? (mw_).x : (mw_).y;                             \
      const int sh = 16 * (nt & 1) + 4 * lg;                                      \
      _Pragma("unroll")                                                           \
      for (int r = 0; r < 4; ++r) {                                               \
        float s = fmaf(a[r], SC, -B4);                                            \
        if ((word >> (sh + r)) & 1) s = -1.0e9f;                                  \
        ssum += __builtin_exp2f(s);                                               \
      }                                                                           \
    }                                                                             \
  }

  // sweep-2 per-tile compute (4 nontemporal stores)
#define COMPUTE2(kt_, buf_, mw_)                                                  \
  {                                                                               \
    f32x4 sc[4];                                                                  \
    _Pragma("unroll")                                                             \
    for (int nt = 0; nt < 4; ++nt) {                                              \
      f32x4 a;                                                                    \
      QKT_CHUNK(nt, buf_, a)                                                      \
      const u32t word = (nt < 2) ? (mw_).x : (mw_).y;                             \
      const int sh = 16 * (nt & 1) + 4 * lg;                                      \
      _Pragma("unroll")                                                           \
      for (int r = 0; r < 4; ++r) {                                               \
        float s = fmaf(a[r], SC, -B4);                                            \
        if ((word >> (sh + r)) & 1) s = -1.0e9f;                                  \
        sc[nt][r] = __builtin_exp2f(s) * inv;                                     \
      }                                                                           \
    }                                                                             \
    _Pragma("unroll")                                                             \
    for (int nt = 0; nt < 4; ++nt) {                                              \
      __builtin_nontemporal_store(sc[nt],                                         \
          (f32x4*)(probs + prow + (kt_) * 64 + nt * 16 + 4 * lg));                \
    }                                                                             \
    FragU pf[2];                                                                  \
    _Pragma("unroll")                                                             \
    for (int c = 0; c < 2; ++c) {                                                 \
      pf[c].g[0] = pkbf2(sc[2 * c][0],     sc[2 * c][1]);                         \
      pf[c].g[1] = pkbf2(sc[2 * c][2],     sc[2 * c][3]);                         \
      pf[c].g[2] = pkbf2(sc[2 * c + 1][0], sc[2 * c + 1][1]);                     \
      pf[c].g[3] = pkbf2(sc[2 * c + 1][2], sc[2 * c + 1][3]);                     \
    }                                                                             \
    __builtin_amdgcn_s_setprio(1);                                                \
    _Pragma("unroll")                                                             \
    for (int c = 0; c < 2; ++c) {                                                 \
      _Pragma("unroll")                                                           \
      for (int n0 = 0; n0 < 4; ++n0) {                                            \
        const int dv = n0 * 16 + lq;                                              \
        const int xv = (lq & 7) * 8;                                              \
        FragU bvv;                                                                \
        bvv.h[0] = *(const ushort4*)&Vb3[buf_][dv * 64 + ((c * 32 + 4 * lg) ^ xv)]; \
        bvv.h[1] = *(const ushort4*)&Vb3[buf_][dv * 64 + ((c * 32 + 4 * lg + 16) ^ xv)]; \
        acco[n0] = __builtin_amdgcn_mfma_f32_16x16x32_bf16(pf[c].v, bvv.v, acco[n0], 0, 0, 0); \
      }                                                                           \
    }                                                                             \
    __builtin_amdgcn_s_setprio(0);                                                \
  }

  float ssum = 0.f;

  // ---------------- sweep 1: K-only, 3-buf, depth-2, masks reg-prefetched ----------------
  STAGE_K(0, 0)
  uint2 mA = *(const uint2*)(mrow + 0);
  STAGE_K(1, 1)
  uint2 mB = *(const uint2*)(mrow + 2);

  for (int kt = 0; kt < 32; kt += 2) {
    // even tile kt
    if (kt == 0) { asm volatile("s_waitcnt vmcnt(0)" ::: "memory"); }
    else         { asm volatile("s_waitcnt vmcnt(3)" ::: "memory"); }
    __builtin_amdgcn_s_barrier();
    {
      uint2 mw = mA;
      if (kt < 30) { STAGE_K(kt + 2, (kt + 2) % 3) mA = *(const uint2*)(mrow + (kt + 2) * 2); }
      COMPUTE1(kt % 3, mw)
    }
    // odd tile kt+1
    if (kt == 0)       { asm volatile("s_waitcnt vmcnt(0)" ::: "memory"); }
    else if (kt == 30) { asm volatile("s_waitcnt vmcnt(0)" ::: "memory"); }
    else               { asm volatile("s_waitcnt vmcnt(3)" ::: "memory"); }
    __builtin_amdgcn_s_barrier();
    {
      uint2 mw = mB;
      if (kt < 30) { STAGE_K(kt + 3, (kt + 3) % 3) mB = *(const uint2*)(mrow + (kt + 3) * 2); }
      COMPUTE1((kt + 1) % 3, mw)
    }
  }

  ssum += __shfl_xor(ssum, 16);
  ssum += __shfl_xor(ssum, 32);
  const float inv = 1.0f / ssum;

  f32x4 acco[4];
#pragma unroll
  for (int i = 0; i < 4; ++i)
#pragma unroll
    for (int r = 0; r < 4; ++r) acco[i][r] = 0.f;

  const size_t prow = ((size_t)bh * SS + qbase + lq) * SS;

  // ---------------- sweep 2: K+V 3-buf depth-2; stores never drained ----------------
  __builtin_amdgcn_s_barrier();          // all waves done reading sweep-1 bufs
  STAGE_K(0, 0) STAGE_V(0, 0)
  mA = *(const uint2*)(mrow + 0);
  STAGE_K(1, 1) STAGE_V(1, 1)
  mB = *(const uint2*)(mrow + 2);

  for (int kt = 0; kt < 32; kt += 2) {
    // even tile kt
    if (kt == 0) { asm volatile("s_waitcnt vmcnt(0)" ::: "memory"); }
    else         { asm volatile("s_waitcnt vmcnt(9)" ::: "memory"); }
    __builtin_amdgcn_s_barrier();
    {
      uint2 mw = mA;
      if (kt < 30) {
        STAGE_K(kt + 2, (kt + 2) % 3) STAGE_V(kt + 2, (kt + 2) % 3)
        mA = *(const uint2*)(mrow + (kt + 2) * 2);
      }
      COMPUTE2(kt, kt % 3, mw)
    }
    // odd tile kt+1
    if (kt == 0)       { asm volatile("s_waitcnt vmcnt(0)" ::: "memory"); }
    else if (kt == 30) { asm volatile("s_waitcnt vmcnt(4)" ::: "memory"); }
    else               { asm volatile("s_waitcnt vmcnt(9)" ::: "memory"); }
    __builtin_amdgcn_s_barrier();
    {
      uint2 mw = mB;
      if (kt < 30) {
        STAGE_K(kt + 3, (kt + 3) % 3) STAGE_V(kt + 3, (kt + 3) % 3)
        mB = *(const uint2*)(mrow + (kt + 3) * 2);
      }
      COMPUTE2(kt + 1, (kt + 1) % 3, mw)
    }
  }

  // ctx epilogue: O[q = qbase+4lg+r][d = h*64 + n0*16 + lq]
  {
    const int h = bh % HH;
    const size_t cbase = (size_t)(b * SS + qbase) * DD + h * 64;
#pragma unroll
    for (int n0 = 0; n0 < 4; ++n0)
#pragma unroll
      for (int r = 0; r < 4; ++r)
        ctx[cbase + (size_t)(4 * lg + r) * DD + n0 * 16 + lq] = acco[n0][r];
  }
#undef STAGE_K
#undef STAGE_V
#undef QKT_CHUNK
#undef COMPUTE1
#undef COMPUTE2
}

extern "C" void kernel_launch(void* const* d_in, const int* in_sizes, int n_in,
                              void* d_out, int out_size, void* d_ws, size_t ws_size,
                              hipStream_t stream)
{
  const float* q   = (const float*)d_in[0];
  const float* k   = (const float*)d_in[1];
  const float* v   = (const float*)d_in[2];
  const void*  msk = d_in[3];
  const float* Wq  = (const float*)d_in[4];
  const float* bq  = (const float*)d_in[5];
  const float* Wk  = (const float*)d_in[6];
  const float* bk  = (const float*)d_in[7];
  const float* Wv  = (const float*)d_in[8];
  const float* bv  = (const float*)d_in[9];
  (void)in_sizes; (void)n_in; (void)out_size; (void)ws_size;

  u16t* Qb = (u16t*)d_ws;
  u16t* Kb = Qb + NE;
  u16t* Vb = Kb + NE;
  u32t* pm = (u32t*)(Vb + NE);                // 8192 rows x 64 words = 2 MB
  int* flag = (int*)(pm + (size_t)BB * SS * 64);

  float* ctx   = (float*)d_out;
  float* probs = ctx + NE;

  // scratch inside probs region (fully overwritten by attn afterwards)
  u16t* Xb = (u16t*)probs;                    // 3 x NE bf16 = 37.7 MB
  u16t* Wt = Xb + (size_t)3 * NE;             // 3 x 768x768 bf16 = 3.5 MB

  detect_kernel<<<1, 256, 0, stream>>>((const u32t*)msk, flag);
  mask_pack_kernel<<<2048, 256, 0, stream>>>(msk, flag, pm);

  cvt_x_kernel<<<dim3(3072, 3), 256, 0, stream>>>(q, k, v, Xb);
  cvt_w_kernel<<<dim3(12, 12, 3), 256, 0, stream>>>(Wq, Wk, Wv, Wt);

  proj_all_kernel<<<dim3(BB * SS / 64, DD / 128, 3), 256, 0, stream>>>(
      Xb, Wt, bq, bk, bv, Qb, Kb, Vb);

  attn_kernel<<<dim3(1536), 256, 0, stream>>>(Qb, Kb, Vb, pm, ctx, probs);
}